// Round 20
// baseline (2913.201 us; speedup 1.0000x reference)
//
#include <hip/hip_runtime.h>
#include <hip/hip_bf16.h>
#include <math.h>

#define EPS_ 1e-5f
#define LOG2E_ 1.4426950408889634f

typedef __attribute__((ext_vector_type(8))) short short8;
typedef __attribute__((ext_vector_type(4))) float f32x4;
typedef __attribute__((ext_vector_type(4))) unsigned short us4;
typedef unsigned short ushort_t;

__device__ inline ushort_t f2b(float x){
  union{ __hip_bfloat16 h; ushort_t u; } c; c.h = __float2bfloat16(x); return c.u;
}
__device__ inline float b2f(ushort_t u){
  union{ unsigned int i; float f; } c; c.i = ((unsigned int)u)<<16; return c.f;
}
__device__ inline void gload_lds16(const void* g, void* l){
  __builtin_amdgcn_global_load_lds((const __attribute__((address_space(1))) void*)g,
                                   (__attribute__((address_space(3))) void*)l, 16, 0, 0);
}
template<int N> __device__ inline void vmwait(){
  asm volatile("s_waitcnt vmcnt(%0)" :: "i"(N) : "memory");
  __builtin_amdgcn_sched_barrier(0);
}
__device__ inline void sbar(){
  __builtin_amdgcn_s_barrier();
  __builtin_amdgcn_sched_barrier(0);
}

// ---------------- reduction helpers ----------------
__device__ inline float wred_sum(float v){
#pragma unroll
  for(int o=32;o>=1;o>>=1) v += __shfl_xor(v,o);
  return v;
}
__device__ inline float wred_max(float v){
#pragma unroll
  for(int o=32;o>=1;o>>=1) v = fmaxf(v,__shfl_xor(v,o));
  return v;
}
__device__ inline float bred256_sum(float v, float* sm){
  v = wred_sum(v);
  if((threadIdx.x&63)==0) sm[threadIdx.x>>6]=v;
  __syncthreads();
  v = sm[0]+sm[1]+sm[2]+sm[3];
  __syncthreads();
  return v;
}
__device__ inline float bred256_max(float v, float* sm){
  v = wred_max(v);
  if((threadIdx.x&63)==0) sm[threadIdx.x>>6]=v;
  __syncthreads();
  v = fmaxf(fmaxf(sm[0],sm[1]),fmaxf(sm[2],sm[3]));
  __syncthreads();
  return v;
}

// ---------------- bf16 MFMA GEMM, counted-vmcnt dbuf, row-major chunk staging --------------
// Staging: consecutive lanes cover consecutive 16B chunks of the SAME row; chunk
// XOR-preswizzled at the GLOBAL source, read back with same XOR -> 2-way (free) LDS.
//   CPR==4: swz = kc ^ ((row>>1)&3)   CPR==8: swz = kc ^ (row&7)
// C = A @ W^T.  EPI: 0 bf16(+bias) | 1 f32+bias+pos | 2 f32 resid | 3 bf16 gelu | 6 PV | 7 f32+bias
#define SWZF(r) ((CPR==8) ? ((r)&7) : (((r)>>1)&3))

#define STAGE_A(DST, K0) { \
  _Pragma("unroll") \
  for(int it=0; it<(BM*BK/(NT*8)); ++it){ \
    int c = it*NT + tid; \
    int row = c >> LCPR, kc = c & (CPR-1); \
    int gm = m0+row; gm = gm<M?gm:M-1; \
    gload_lds16(Ab + (long)gm*lda + (K0) + ((kc ^ SWZF(row))*8), (DST) + (it*NT + wid*64)*8); } }

#define STAGE_B(DST, K0) { \
  _Pragma("unroll") \
  for(int it=0; it<(BN*BK/(NT*8)); ++it){ \
    int c = it*NT + tid; \
    int row = c >> LCPR, kc = c & (CPR-1); \
    int gn = n0+row; gn = gn<N?gn:N-1; \
    gload_lds16(Wb + (long)gn*ldw + (K0) + ((kc ^ SWZF(row))*8), (DST) + (it*NT + wid*64)*8); } }

#define COMPUTE(SRCA, SRCB) { \
  const short8* pA = (const short8*)(SRCA); \
  const short8* pB = (const short8*)(SRCB); \
  _Pragma("unroll") \
  for(int ks=0; ks<BK/32; ++ks){ \
    short8 a[FM], b[FN]; \
    _Pragma("unroll") \
    for(int i=0;i<FM;++i){ \
      int rA = wr*PWM + i*16 + l15; \
      a[i] = pA[rA*CPR + ((ks*4+l4) ^ SWZF(rA))]; } \
    _Pragma("unroll") \
    for(int j=0;j<FN;++j){ \
      int rB = wc*PWN + j*16 + l15; \
      b[j] = pB[rB*CPR + ((ks*4+l4) ^ SWZF(rB))]; } \
    __builtin_amdgcn_s_setprio(1); \
    _Pragma("unroll") \
    for(int i=0;i<FM;++i) \
      _Pragma("unroll") \
      for(int j=0;j<FN;++j) \
        acc[i][j] = __builtin_amdgcn_mfma_f32_16x16x32_bf16(a[i], b[j], acc[i][j], 0,0,0); \
    __builtin_amdgcn_s_setprio(0); } }

template<int BM,int BN,int BK,int NT,int WR,int WC,int EPI>
__global__ __launch_bounds__(NT) void gemm_bf(
    const ushort_t* __restrict__ A, int lda, long sAo, long sAi,
    const ushort_t* __restrict__ W, int ldw, long sWo, long sWi,
    const float* __restrict__ bias,
    void* __restrict__ Cv, int ldc, long sC,
    int M, int N, int K, int nInner,
    const float* __restrict__ aux)
{
  constexpr int PWM = BM/WR, PWN = BN/WC;
  constexpr int FM = PWM/16, FN = PWN/16;
  constexpr int CPR = BK/8;
  constexpr int LCPR = (BK==64)?3:2;
  constexpr int NL  = (BM+BN)*BK/(NT*8);
  constexpr int SMEMB = (BM+BN)*BK*2*2;

  __shared__ __align__(16) ushort_t smem[(BM+BN)*BK*2];
  ushort_t* lA0 = smem;
  ushort_t* lB0 = lA0 + BM*BK;
  ushort_t* lA1 = lB0 + BN*BK;
  ushort_t* lB1 = lA1 + BM*BK;

  const int tid = threadIdx.x;
  const int lane = tid & 63, wid = tid >> 6;
  const int wr = wid / WC, wc = wid % WC;
  const int l15 = lane & 15, l4 = lane >> 4;
  const int z = blockIdx.z;
  const int zo = z / nInner, zi = z - zo*nInner;

  int bx = blockIdx.x, by = blockIdx.y;
  if(gridDim.z==1){
    int gx = gridDim.x;
    int nwg = gx*gridDim.y;
    int orig = by*gx + bx;
    int xcd = orig & 7, idx = orig >> 3;
    int q = nwg >> 3, r = nwg & 7;
    int neu = xcd*q + (xcd<r?xcd:r) + idx;
    bx = neu % gx; by = neu / gx;
  }

  const ushort_t* Ab = A + zo*sAo + zi*sAi;
  const ushort_t* Wb = W + zo*sWo + zi*sWi;
  const int m0 = by*BM, n0 = bx*BN;

  f32x4 acc[FM][FN];
#pragma unroll
  for(int i=0;i<FM;++i)
#pragma unroll
    for(int j=0;j<FN;++j) acc[i][j] = {0.f,0.f,0.f,0.f};

  const int nt = K/BK;
  STAGE_A(lA0, 0); STAGE_B(lB0, 0);
  if(nt>1){ STAGE_A(lA1, BK); STAGE_B(lB1, BK); vmwait<NL>(); }
  else vmwait<0>();
  sbar();

  for(int t=0; t<nt; ++t){
    if((t&1)==0){ COMPUTE(lA0, lB0); } else { COMPUTE(lA1, lB1); }
    if(t+1 < nt){
      sbar();
      if(t+2 < nt){
        int k0 = (t+2)*BK;
        if((t&1)==0){ STAGE_A(lA0, k0); STAGE_B(lB0, k0); }
        else        { STAGE_A(lA1, k0); STAGE_B(lB1, k0); }
        vmwait<NL>();
      } else {
        vmwait<0>();
      }
      sbar();
    }
  }

  if(EPI==0 || EPI==3 || EPI==6){
#pragma unroll
    for(int i=0;i<FM;++i){
#pragma unroll
      for(int r=0;r<4;++r){
        int m = m0 + wr*PWM + i*16 + l4*4 + r;
        if(m>=M) continue;
#pragma unroll
        for(int j=0;j<FN;++j){
          int n = n0 + wc*PWN + j*16 + l15;
          if(n>=N) continue;
          float v = acc[i][j][r];
          if(bias) v += bias[n];
          if(EPI==3) v = 0.5f*v*(1.f+erff(v*0.70710678118f));
          if(EPI==6){
            int bq = z>>3, hh = z&7;
            ((ushort_t*)Cv)[((long)(bq*196+m))*384 + hh*48 + n] = f2b(v);
          } else {
            ((ushort_t*)Cv)[(long)z*sC + (long)m*ldc + n] = f2b(v);
          }
        }
      }
    }
  } else {
    constexpr int STLD = BN+4;
    constexpr int STGR = (BM*STLD*4 <= SMEMB) ? BM :
                         ((BM/2*STLD*4 <= SMEMB) ? BM/2 : BM/4);
    constexpr int NPASS = BM/STGR;
    float* st = (float*)smem;
    __syncthreads();
    for(int p=0; p<NPASS; ++p){
      if(p) __syncthreads();
#pragma unroll
      for(int i=0;i<FM;++i){
        int rbase = wr*PWM + i*16 + l4*4 - p*STGR;
#pragma unroll
        for(int r=0;r<4;++r){
          int lr = rbase + r;
          if(lr < 0 || lr >= STGR) continue;
#pragma unroll
          for(int j=0;j<FN;++j)
            st[lr*STLD + wc*PWN + j*16 + l15] = acc[i][j][r];
        }
      }
      __syncthreads();
      const int total = STGR*BN/4;
      for(int c=tid; c<total; c+=NT){
        int row = c/(BN/4), colc = c - row*(BN/4);
        int gm = m0 + p*STGR + row;
        if(gm >= M) continue;
        int nb = n0 + colc*4;
        if(nb >= N) continue;
        f32x4 v = *(f32x4*)&st[row*STLD + colc*4];
        float* cp = (float*)Cv + (long)gm*ldc + nb;
        f32x4 bs = bias ? *(const f32x4*)(bias+nb) : f32x4{0,0,0,0};
        if(EPI==1){
          const f32x4 ax = *(const f32x4*)(aux + (long)(gm%196)*ldc + nb);
          *(f32x4*)cp = v + bs + ax;
        } else if(EPI==2){
          const f32x4 ax = *(const f32x4*)(aux + nb);
          f32x4 h = *(f32x4*)cp;
          h += ax*(v + bs);
          *(f32x4*)cp = h;
        } else {
          *(f32x4*)cp = v + bs;
        }
      }
    }
  }
}

// ---------------- qk_logits: per (b,h), S = q @ k^T -> attn[bh][196][224] ----------------
__global__ __launch_bounds__(256) void qk_logits(
  const ushort_t* __restrict__ qkvb, ushort_t* __restrict__ attn)
{
  __shared__ __align__(16) ushort_t Q[196*64];
  __shared__ __align__(16) ushort_t Kl[196*64];
  int bh = blockIdx.x; int b = bh>>3, h = bh&7;
  int tid = threadIdx.x, lane = tid&63, w = tid>>6;
  int l15 = lane&15, l4 = lane>>4;
  const ushort_t* qs = qkvb + (long)(b*196)*1152 + h*48;
  const ushort_t* ks = qs + 384;
  for(int idx=tid; idx<196*8; idx+=256){
    int row = idx>>3, c = idx&7;
    int sw = (c*16) ^ ((row&7)<<4);
    short8 t0, t1;
    if(c<6){
      t0 = *(const short8*)(qs + (long)row*1152 + c*8);
      t1 = *(const short8*)(ks + (long)row*1152 + c*8);
    } else {
      t0 = short8{0,0,0,0,0,0,0,0}; t1 = t0;
    }
    *(short8*)((char*)Q  + row*128 + sw) = t0;
    *(short8*)((char*)Kl + row*128 + sw) = t1;
  }
  __syncthreads();
  ushort_t* Srow = attn + (long)bh*196*224;
  for(int t2=w; t2<169; t2+=4){
    int mt = t2/13, nt = t2-mt*13;
    int arow = mt*16+l15; if(arow>195) arow=195;
    int brow = nt*16+l15; if(brow>195) brow=195;
    f32x4 acc = {0.f,0.f,0.f,0.f};
#pragma unroll
    for(int ks2=0;ks2<2;++ks2){
      short8 a  = *(const short8*)((char*)Q  + arow*128 + ((ks2*64 + l4*16) ^ ((arow&7)<<4)));
      short8 bf = *(const short8*)((char*)Kl + brow*128 + ((ks2*64 + l4*16) ^ ((brow&7)<<4)));
      acc = __builtin_amdgcn_mfma_f32_16x16x32_bf16(a, bf, acc, 0,0,0);
    }
#pragma unroll
    for(int r=0;r<4;++r){
      int m = mt*16 + l4*4 + r, n = nt*16 + l15;
      if(m<196 && n<196) Srow[(long)m*224 + n] = f2b(acc[r]);
    }
  }
}

// ---------------- LayerNorm: one wave per row, 4 rows/block ----------------
__global__ __launch_bounds__(256) void ln_kernel(
  const float* __restrict__ X, ushort_t* __restrict__ Y,
  const float* __restrict__ g, const float* __restrict__ b, int rows)
{
  int r = blockIdx.x*4 + (threadIdx.x>>6);
  if(r>=rows) return;
  int t = threadIdx.x & 63;
  const float* xr = X + (long)r*384;
  ushort_t* yr = Y + (long)r*384;
  f32x4  v0 = *(const f32x4*)(xr + t*4);
  float2 v1 = *(const float2*)(xr + 256 + t*2);
  float s = v0[0]+v0[1]+v0[2]+v0[3]+v1.x+v1.y;
  s = wred_sum(s);
  float mean = s*(1.f/384.f);
  float d0=v0[0]-mean, d1=v0[1]-mean, d2=v0[2]-mean, d3=v0[3]-mean,
        d4=v1.x-mean, d5=v1.y-mean;
  float ss = d0*d0+d1*d1+d2*d2+d3*d3+d4*d4+d5*d5;
  ss = wred_sum(ss);
  float rstd = rsqrtf(ss*(1.f/384.f)+EPS_);
  f32x4  g0 = *(const f32x4*)(g + t*4);
  float2 g1 = *(const float2*)(g + 256 + t*2);
  f32x4  b0 = *(const f32x4*)(b + t*4);
  float2 b1 = *(const float2*)(b + 256 + t*2);
  us4 o0;
  o0[0]=f2b(d0*rstd*g0[0]+b0[0]); o0[1]=f2b(d1*rstd*g0[1]+b0[1]);
  o0[2]=f2b(d2*rstd*g0[2]+b0[2]); o0[3]=f2b(d3*rstd*g0[3]+b0[3]);
  *(us4*)(yr + t*4) = o0;
  unsigned int ot = (unsigned int)f2b(d4*rstd*g1.x+b1.x) |
                    ((unsigned int)f2b(d5*rstd*g1.y+b1.y)<<16);
  *(unsigned int*)(yr + 256 + t*2) = ot;
}

// ---------------- talking-heads mix + softmax + mix, in place ----------------
__global__ __launch_bounds__(256) void th_softmax(
  ushort_t* attn,
  const float* __restrict__ plw, const float* __restrict__ plb,
  const float* __restrict__ pww, const float* __restrict__ pwb)
{
  __shared__ float swl[64], sww[64], sbl[8], sbw[8];
  int t = threadIdx.x;
  if(t<64){ swl[t]=plw[t]; sww[t]=pww[t]; }
  if(t<8){ sbl[t]=plb[t]; sbw[t]=pwb[t]; }
  __syncthreads();
  int wid = t>>6, lane = t&63;
  int rid = blockIdx.x*4 + wid;
  int b = rid/196, n = rid - b*196;
  long rbase = ((long)(b*8)*196 + n)*224;
  int col0 = lane*4;
  bool inrow = col0 < 224;
  bool act = col0 < 196;
  float L[8][4];
#pragma unroll
  for(int h=0;h<8;++h){
    us4 v = inrow ? *(const us4*)(attn + rbase + (long)h*43904 + col0) : us4{0,0,0,0};
#pragma unroll
    for(int c=0;c<4;++c) L[h][c] = b2f(v[c]);
  }
  float P[8][4];
#pragma unroll
  for(int g=0; g<8; ++g){
    float mv[4];
#pragma unroll
    for(int c=0;c<4;++c){
      float v = sbl[g];
#pragma unroll
      for(int h=0;h<8;++h) v += L[h][c]*swl[g*8+h];
      mv[c] = act ? v : -3.0e38f;
    }
    float mx = fmaxf(fmaxf(mv[0],mv[1]),fmaxf(mv[2],mv[3]));
    mx = wred_max(mx);
    float sum = 0.f;
#pragma unroll
    for(int c=0;c<4;++c){
      float e = act ? exp2f((mv[c]-mx)*LOG2E_) : 0.f;
      P[g][c] = e; sum += e;
    }
    sum = wred_sum(sum);
    float rinv = 1.f/sum;
#pragma unroll
    for(int c=0;c<4;++c) P[g][c] *= rinv;
  }
#pragma unroll
  for(int g2=0; g2<8; ++g2){
    us4 st;
#pragma unroll
    for(int c=0;c<4;++c){
      float v = sbw[g2];
#pragma unroll
      for(int g=0; g<8; ++g) v += P[g][c]*sww[g2*8+g];
      st[c] = f2b(v);
    }
    if(act) *(us4*)(attn + ((long)(b*8+g2)*196 + n)*224 + col0) = st;
  }
}

// ---------------- V transpose: qkvb v-cols -> vT[bh][48][224] ----------------
__global__ __launch_bounds__(256) void v_transpose(
  const ushort_t* __restrict__ qkvb, ushort_t* __restrict__ vT)
{
  int bh = blockIdx.x; int b = bh>>3, h = bh&7;
  int p0 = blockIdx.y*98;
  __shared__ ushort_t tile[98*49];
  int t = threadIdx.x;
  const ushort_t* src = qkvb + (long)(b*196+p0)*1152 + 768 + h*48;
  for(int idx=t; idx<98*48; idx+=256){
    int p = idx/48, d = idx - p*48;
    tile[p*49+d] = src[(long)p*1152 + d];
  }
  __syncthreads();
  ushort_t* dst = vT + ((long)bh*48)*224 + p0;
  for(int idx=t; idx<48*98; idx+=256){
    int d = idx/98, p = idx - d*98;
    dst[(long)d*224 + p] = tile[p*49+d];
  }
}

// ---------------- class-attention (1 query token), kv packed [12608][768] ----------------
__global__ __launch_bounds__(256) void ca_attn_kernel(
  const ushort_t* __restrict__ q, const ushort_t* __restrict__ kv,
  ushort_t* __restrict__ o)
{
  int bh = blockIdx.x; int b = bh>>3, h = bh&7;
  int t = threadIdx.x;
  __shared__ float qs[48], p[197], sm[4];
  if(t<48) qs[t] = b2f(q[(long)b*384 + h*48 + t]) * 0.14433756729740643f;
  __syncthreads();
  float logit = -3.0e38f;
  if(t<197){
    const ushort_t* kr = kv + ((long)(b*197+t))*768 + h*48;
    float s=0.f;
#pragma unroll
    for(int d=0;d<48;++d) s += qs[d]*b2f(kr[d]);
    logit = s;
  }
  float mx = bred256_max(logit, sm);
  float e = (t<197)? expf(logit-mx):0.f;
  float ssum = bred256_sum(e, sm);
  if(t<197) p[t] = e/ssum;
  __syncthreads();
  if(t<48){
    const ushort_t* vr = kv + (long)b*197*768 + 384 + h*48 + t;
    float s=0.f;
    for(int m=0;m<197;++m) s += p[m]*b2f(vr[(long)m*768]);
    o[(long)b*384 + h*48 + t] = f2b(s);
  }
}

// ---------------- small elementwise kernels ----------------
__global__ void patch_extract(const float* __restrict__ x, ushort_t* __restrict__ xp){
  long i = (long)blockIdx.x*256 + threadIdx.x;
  if(i >= (long)12544*768) return;
  int kk = (int)(i % 768); long row = i/768;
  int b = (int)(row/196), pidx = (int)(row%196);
  int gy = pidx/14, gx = pidx%14;
  int ch = kk/256, r = kk%256, py = r/16, px = r%16;
  xp[i] = f2b(x[((long)(b*3+ch)*224 + gy*16+py)*224 + gx*16+px]);
}
__global__ void build_u(const float* __restrict__ h, float* __restrict__ u){
  long i = (long)blockIdx.x*256 + threadIdx.x;
  if(i >= (long)12544*384) return;
  int c = (int)(i % 384); long rp = i/384;
  int b = (int)(rp/196), p = (int)(rp%196);
  u[((long)b*197 + 1 + p)*384 + c] = h[i];
}
__global__ void set_row0(float* __restrict__ u, const float* __restrict__ cls){
  int i = blockIdx.x*256 + threadIdx.x;
  if(i >= 64*384) return;
  int b = i/384, c = i%384;
  u[(long)b*197*384 + c] = cls[i];
}
__global__ void init_cls(float* __restrict__ cls, const float* __restrict__ tok){
  int i = blockIdx.x*256 + threadIdx.x;
  if(i >= 64*384) return;
  cls[i] = tok[i%384];
}
__global__ void conv_bf(const float* __restrict__ s, ushort_t* __restrict__ d, int n){
  int i = (blockIdx.x*256 + threadIdx.x)*4;
  if(i+3 < n){
    float4 v = *(const float4*)(s+i);
    d[i]=f2b(v.x); d[i+1]=f2b(v.y); d[i+2]=f2b(v.z); d[i+3]=f2b(v.w);
  } else {
    for(int j=i;j<n;++j) d[j]=f2b(s[j]);
  }
}
__global__ void conv_qkv(const float* __restrict__ w, ushort_t* __restrict__ out, float scl){
  long i = (long)blockIdx.x*256 + threadIdx.x;
  if(i >= 5308416L) return;
  long r = i / 384;
  int n = (int)(r % 1152);
  float v = w[i];
  if(n < 384) v *= scl;
  out[i] = f2b(v);
}

// ---------------- host orchestration ----------------
extern "C" void kernel_launch(void* const* d_in, const int* in_sizes, int n_in,
                              void* d_out, int out_size, void* d_ws, size_t ws_size,
                              hipStream_t stream)
{
  const float* in_x     = (const float*)d_in[0];
  const float* patch_w  = (const float*)d_in[1];
  const float* patch_b  = (const float*)d_in[2];
  const float* cls_tok  = (const float*)d_in[3];
  const float* pos_emb  = (const float*)d_in[4];
  const float* ln1_g = (const float*)d_in[5];
  const float* ln1_b = (const float*)d_in[6];
  const float* qkv_w = (const float*)d_in[7];
  const float* proj_w = (const float*)d_in[8];
  const float* proj_b = (const float*)d_in[9];
  const float* pl_w = (const float*)d_in[10];
  const float* pl_b = (const float*)d_in[11];
  const float* pw_w = (const float*)d_in[12];
  const float* pw_b = (const float*)d_in[13];
  const float* ln2_g = (const float*)d_in[14];
  const float* ln2_b = (const float*)d_in[15];
  const float* fc1_w = (const float*)d_in[16];
  const float* fc1_b = (const float*)d_in[17];
  const float* fc2_w = (const float*)d_in[18];
  const float* fc2_b = (const float*)d_in[19];
  const float* g1 = (const float*)d_in[20];
  const float* g2 = (const float*)d_in[21];
  const float* ca_ln1_g = (const float*)d_in[22];
  const float* ca_ln1_b = (const float*)d_in[23];
  const float* ca_q_w = (const float*)d_in[24];
  const float* ca_k_w = (const float*)d_in[25];
  const float* ca_v_w = (const float*)d_in[26];
  const float* ca_proj_w = (const float*)d_in[27];
  const float* ca_proj_b = (const float*)d_in[28];
  const float* ca_ln2_g = (const float*)d_in[29];
  const float* ca_ln2_b = (const float*)d_in[30];
  const float* ca_fc1_w = (const float*)d_in[31];
  const float* ca_fc1_b = (const float*)d_in[32];
  const float* ca_fc2_w = (const float*)d_in[33];
  const float* ca_fc2_b = (const float*)d_in[34];
  const float* ca_g1 = (const float*)d_in[35];
  const float* ca_g2 = (const float*)d_in[36];
  const float* norm_g = (const float*)d_in[37];
  const float* norm_b = (const float*)d_in[38];
  const float* head_w = (const float*)d_in[39];
  const float* head_b = (const float*)d_in[40];
  float* out = (float*)d_out;

  // ---- workspace layout (bytes) ----
  char* W0 = (char*)d_ws;
  float*    h_buf  = (float*)   (W0 + 0);          // 12544*384 f32
  ushort_t* attn   = (ushort_t*)(W0 + 19267584);   // [512][196][224] bf16 (aliases u/xp)
  float*    u_buf  = (float*)attn;
  ushort_t* xp_bf  = (ushort_t*)attn;
  float*    cls    = (float*)   (W0 + 64225280);
  ushort_t* ln_bf  = (ushort_t*)(W0 + 64323584);   // 12608*384 bf16
  ushort_t* qkvb   = (ushort_t*)(W0 + 74006528);   // [12544][1152] bf16
  ushort_t* vT     = (ushort_t*)(W0 + 102907904);  // [512][48][224] bf16
  ushort_t* wb     = (ushort_t*)(W0 + 113917952);  // weights
  ushort_t* cq_bf  = (ushort_t*)(W0 + 164820992);
  ushort_t* oca_bf = (ushort_t*)(W0 + 164870144);
  ushort_t* clsln  = (ushort_t*)(W0 + 164919296);
  ushort_t* mlpca  = (ushort_t*)(W0 + 164968448);
  ushort_t* mlp_bf = (ushort_t*)(W0 + 165165056);  // [12544][1536] bf16
  ushort_t* o_bf   = qkvb;                         // o [12544][384]
  ushort_t* kv_bf  = qkvb;                         // CA kv [12608][768]

  const long WP=0, WQKV=294912, WPROJ=5603328, WFC1=7372800, WFC2=14450688,
             WCAQ=21528576, WCAK=21823488, WCAP=22413312,
             WCAF1=22708224, WCAF2=23887872, WHEAD=25067520;

  const float scl = 0.14433756729740643f;  // 48^-0.5
  dim3 blk(256);

  // zero vT once (cols >=196 must stay 0)
  hipMemsetAsync(vT, 0, 11010048, stream);

  // weights -> bf16 (qkv natural layout, q rows prescaled)
  conv_qkv<<<dim3(20736),blk,0,stream>>>(qkv_w, wb+WQKV, scl);
  {
    const float* src[11] = {patch_w,proj_w,fc1_w,fc2_w,ca_q_w,ca_k_w,ca_v_w,
                            ca_proj_w,ca_fc1_w,ca_fc2_w,head_w};
    const long  off[11] = {WP,WPROJ,WFC1,WFC2,WCAQ,WCAK,WCAK+294912,WCAP,WCAF1,WCAF2,WHEAD};
    const long  cnt[11] = {294912,1769472,7077888,7077888,294912,294912,294912,
                           294912,1179648,1179648,384000};
    for(int i=0;i<11;++i)
      conv_bf<<<dim3((unsigned)((cnt[i]/4+255)/256)),blk,0,stream>>>(src[i], wb+off[i], (int)cnt[i]);
  }

  // 1. patch embed (xp aliases attn; runs before attn memset)
  {
    long n = (long)12544*768;
    patch_extract<<<dim3((unsigned)((n+255)/256)), blk, 0, stream>>>(in_x, xp_bf);
  }
  gemm_bf<128,128,32,512,4,2,1><<<dim3(3,98,1),dim3(512),0,stream>>>(xp_bf,768,0,0, wb+WP,768,0,0, patch_b,
      h_buf,384,0, 12544,384,768,1, pos_emb);

  // zero attn once: pads (col>=196) stay zero across all layers
  hipMemsetAsync(attn, 0, 44957696, stream);

  // 2. twelve talking-heads SA blocks
  for(int d=0; d<12; ++d){
    ln_kernel<<<3136,blk,0,stream>>>(h_buf, ln_bf, ln1_g+d*384, ln1_b+d*384, 12544);
    gemm_bf<128,128,32,512,4,2,0><<<dim3(9,98,1),dim3(512),0,stream>>>(ln_bf,384,0,0,
        wb+WQKV+(long)d*442368,384,0,0, nullptr,
        qkvb,1152,0, 12544,1152,384,1, nullptr);
    v_transpose<<<dim3(512,2,1),blk,0,stream>>>(qkvb, vT);
    qk_logits<<<dim3(512),blk,0,stream>>>(qkvb, attn);
    th_softmax<<<3136,blk,0,stream>>>(attn, pl_w+d*64, pl_b+d*8, pw_w+d*64, pw_b+d*8);
    gemm_bf<64,64,32,256,2,2,6><<<dim3(1,4,512),blk,0,stream>>>(attn,224,43904L,0L,
        vT,224,10752L,0L, nullptr,
        o_bf,0,0, 196,48,224,1, nullptr);
    gemm_bf<128,128,32,512,4,2,2><<<dim3(3,98,1),dim3(512),0,stream>>>(o_bf,384,0,0,
        wb+WPROJ+(long)d*147456,384,0,0, proj_b+d*384,
        h_buf,384,0, 12544,384,384,1, g1+d*384);
    ln_kernel<<<3136,blk,0,stream>>>(h_buf, ln_bf, ln2_g+d*384, ln2_b+d*384, 12544);
    gemm_bf<128,128,32,512,4,2,3><<<dim3(12,98,1),dim3(512),0,stream>>>(ln_bf,384,0,0,
        wb+WFC1+(long)d*589824,384,0,0, fc1_b+d*1536,
        mlp_bf,1536,0, 12544,1536,384,1, nullptr);
    gemm_bf<128,128,32,512,4,2,2><<<dim3(3,98,1),dim3(512),0,stream>>>(mlp_bf,1536,0,0,
        wb+WFC2+(long)d*589824,1536,0,0, fc2_b+d*384,
        h_buf,384,0, 12544,384,1536,1, g2+d*384);
  }

  // 3. two class-attention blocks
  init_cls<<<96,blk,0,stream>>>(cls, cls_tok);
  build_u<<<dim3((unsigned)(((long)12544*384+255)/256)),blk,0,stream>>>(h_buf, u_buf);
  for(int d=0; d<2; ++d){
    set_row0<<<96,blk,0,stream>>>(u_buf, cls);
    ln_kernel<<<3152,blk,0,stream>>>(u_buf, ln_bf, ca_ln1_g+d*384, ca_ln1_b+d*384, 12608);
    gemm_bf<64,64,64,256,2,2,0><<<dim3(6,1,1),blk,0,stream>>>(ln_bf,75648,0,0,
        wb+WCAQ+(long)d*147456,384,0,0, nullptr,
        cq_bf,384,0, 64,384,384,1, nullptr);
    gemm_bf<128,128,32,512,4,2,0><<<dim3(6,99,1),dim3(512),0,stream>>>(ln_bf,384,0,0,
        wb+WCAK+(long)d*147456,384,0,0, nullptr,
        kv_bf,768,0, 12608,768,384,1, nullptr);
    ca_attn_kernel<<<512,blk,0,stream>>>(cq_bf, kv_bf, oca_bf);
    gemm_bf<64,64,64,256,2,2,2><<<dim3(6,1,1),blk,0,stream>>>(oca_bf,384,0,0,
        wb+WCAP+(long)d*147456,384,0,0, ca_proj_b+d*384,
        cls,384,0, 64,384,384,1, ca_g1+d*384);
    ln_kernel<<<16,blk,0,stream>>>(cls, clsln, ca_ln2_g+d*384, ca_ln2_b+d*384, 64);
    gemm_bf<64,64,64,256,2,2,3><<<dim3(24,1,1),blk,0,stream>>>(clsln,384,0,0,
        wb+WCAF1+(long)d*589824,384,0,0, ca_fc1_b+d*1536,
        mlpca,1536,0, 64,1536,384,1, nullptr);
    gemm_bf<64,64,64,256,2,2,2><<<dim3(6,1,1),blk,0,stream>>>(mlpca,1536,0,0,
        wb+WCAF2+(long)d*589824,1536,0,0, ca_fc2_b+d*384,
        cls,384,0, 64,384,1536,1, ca_g2+d*384);
  }

  // 4. final LN (cls rows) + head
  ln_kernel<<<16,blk,0,stream>>>(cls, clsln, norm_g, norm_b, 64);
  gemm_bf<64,64,64,256,2,2,7><<<dim3(16,1,1),blk,0,stream>>>(clsln,384,0,0, wb+WHEAD,384,0,0, head_b,
      out,1000,0, 64,1000,384,1, nullptr);
}

// Round 21
// 2784.515 us; speedup vs baseline: 1.0462x; 1.0462x over previous
//
#include <hip/hip_runtime.h>
#include <hip/hip_bf16.h>
#include <math.h>

#define EPS_ 1e-5f
#define LOG2E_ 1.4426950408889634f

typedef __attribute__((ext_vector_type(8))) short short8;
typedef __attribute__((ext_vector_type(4))) float f32x4;
typedef __attribute__((ext_vector_type(4))) unsigned short us4;
typedef unsigned short ushort_t;

__device__ inline ushort_t f2b(float x){
  union{ __hip_bfloat16 h; ushort_t u; } c; c.h = __float2bfloat16(x); return c.u;
}
__device__ inline float b2f(ushort_t u){
  union{ unsigned int i; float f; } c; c.i = ((unsigned int)u)<<16; return c.f;
}
__device__ inline void gload_lds16(const void* g, void* l){
  __builtin_amdgcn_global_load_lds((const __attribute__((address_space(1))) void*)g,
                                   (__attribute__((address_space(3))) void*)l, 16, 0, 0);
}
template<int N> __device__ inline void vmwait(){
  asm volatile("s_waitcnt vmcnt(%0)" :: "i"(N) : "memory");
  __builtin_amdgcn_sched_barrier(0);
}
__device__ inline void sbar(){
  __builtin_amdgcn_s_barrier();
  __builtin_amdgcn_sched_barrier(0);
}

// ---------------- reduction helpers ----------------
__device__ inline float wred_sum(float v){
#pragma unroll
  for(int o=32;o>=1;o>>=1) v += __shfl_xor(v,o);
  return v;
}
__device__ inline float wred_max(float v){
#pragma unroll
  for(int o=32;o>=1;o>>=1) v = fmaxf(v,__shfl_xor(v,o));
  return v;
}
__device__ inline float bred256_sum(float v, float* sm){
  v = wred_sum(v);
  if((threadIdx.x&63)==0) sm[threadIdx.x>>6]=v;
  __syncthreads();
  v = sm[0]+sm[1]+sm[2]+sm[3];
  __syncthreads();
  return v;
}
__device__ inline float bred256_max(float v, float* sm){
  v = wred_max(v);
  if((threadIdx.x&63)==0) sm[threadIdx.x>>6]=v;
  __syncthreads();
  v = fmaxf(fmaxf(sm[0],sm[1]),fmaxf(sm[2],sm[3]));
  __syncthreads();
  return v;
}

// ---------------- bf16 MFMA GEMM, counted-vmcnt dbuf, row-major chunk staging --------------
// Staging: consecutive lanes cover consecutive 16B chunks of the SAME row; chunk
// XOR-preswizzled at the GLOBAL source, read back with same XOR -> 2-way (free) LDS.
//   CPR==4: swz = kc ^ ((row>>1)&3)   CPR==8: swz = kc ^ (row&7)
// C = A @ W^T.  EPI: 0 bf16(+bias) | 1 f32+bias+pos | 2 f32 resid | 3 bf16 gelu | 6 PV | 7 f32+bias
#define SWZF(r) ((CPR==8) ? ((r)&7) : (((r)>>1)&3))

#define STAGE_A(DST, K0) { \
  _Pragma("unroll") \
  for(int it=0; it<(BM*BK/(NT*8)); ++it){ \
    int c = it*NT + tid; \
    int row = c >> LCPR, kc = c & (CPR-1); \
    int gm = m0+row; gm = gm<M?gm:M-1; \
    gload_lds16(Ab + (long)gm*lda + (K0) + ((kc ^ SWZF(row))*8), (DST) + (it*NT + wid*64)*8); } }

#define STAGE_B(DST, K0) { \
  _Pragma("unroll") \
  for(int it=0; it<(BN*BK/(NT*8)); ++it){ \
    int c = it*NT + tid; \
    int row = c >> LCPR, kc = c & (CPR-1); \
    int gn = n0+row; gn = gn<N?gn:N-1; \
    gload_lds16(Wb + (long)gn*ldw + (K0) + ((kc ^ SWZF(row))*8), (DST) + (it*NT + wid*64)*8); } }

#define COMPUTE(SRCA, SRCB) { \
  const short8* pA = (const short8*)(SRCA); \
  const short8* pB = (const short8*)(SRCB); \
  _Pragma("unroll") \
  for(int ks=0; ks<BK/32; ++ks){ \
    short8 a[FM], b[FN]; \
    _Pragma("unroll") \
    for(int i=0;i<FM;++i){ \
      int rA = wr*PWM + i*16 + l15; \
      a[i] = pA[rA*CPR + ((ks*4+l4) ^ SWZF(rA))]; } \
    _Pragma("unroll") \
    for(int j=0;j<FN;++j){ \
      int rB = wc*PWN + j*16 + l15; \
      b[j] = pB[rB*CPR + ((ks*4+l4) ^ SWZF(rB))]; } \
    __builtin_amdgcn_s_setprio(1); \
    _Pragma("unroll") \
    for(int i=0;i<FM;++i) \
      _Pragma("unroll") \
      for(int j=0;j<FN;++j) \
        acc[i][j] = __builtin_amdgcn_mfma_f32_16x16x32_bf16(a[i], b[j], acc[i][j], 0,0,0); \
    __builtin_amdgcn_s_setprio(0); } }

template<int BM,int BN,int BK,int NT,int WR,int WC,int EPI>
__global__ __launch_bounds__(NT) void gemm_bf(
    const ushort_t* __restrict__ A, int lda, long sAo, long sAi,
    const ushort_t* __restrict__ W, int ldw, long sWo, long sWi,
    const float* __restrict__ bias,
    void* __restrict__ Cv, int ldc, long sC,
    int M, int N, int K, int nInner,
    const float* __restrict__ aux)
{
  constexpr int PWM = BM/WR, PWN = BN/WC;
  constexpr int FM = PWM/16, FN = PWN/16;
  constexpr int CPR = BK/8;
  constexpr int LCPR = (BK==64)?3:2;
  constexpr int NL  = (BM+BN)*BK/(NT*8);
  constexpr int SMEMB = (BM+BN)*BK*2*2;

  __shared__ __align__(16) ushort_t smem[(BM+BN)*BK*2];
  ushort_t* lA0 = smem;
  ushort_t* lB0 = lA0 + BM*BK;
  ushort_t* lA1 = lB0 + BN*BK;
  ushort_t* lB1 = lA1 + BM*BK;

  const int tid = threadIdx.x;
  const int lane = tid & 63, wid = tid >> 6;
  const int wr = wid / WC, wc = wid % WC;
  const int l15 = lane & 15, l4 = lane >> 4;
  const int z = blockIdx.z;
  const int zo = z / nInner, zi = z - zo*nInner;

  int bx = blockIdx.x, by = blockIdx.y;
  if(gridDim.z==1){
    int gx = gridDim.x;
    int nwg = gx*gridDim.y;
    int orig = by*gx + bx;
    int xcd = orig & 7, idx = orig >> 3;
    int q = nwg >> 3, r = nwg & 7;
    int neu = xcd*q + (xcd<r?xcd:r) + idx;
    bx = neu % gx; by = neu / gx;
  }

  const ushort_t* Ab = A + zo*sAo + zi*sAi;
  const ushort_t* Wb = W + zo*sWo + zi*sWi;
  const int m0 = by*BM, n0 = bx*BN;

  f32x4 acc[FM][FN];
#pragma unroll
  for(int i=0;i<FM;++i)
#pragma unroll
    for(int j=0;j<FN;++j) acc[i][j] = {0.f,0.f,0.f,0.f};

  const int nt = K/BK;
  STAGE_A(lA0, 0); STAGE_B(lB0, 0);
  if(nt>1){ STAGE_A(lA1, BK); STAGE_B(lB1, BK); vmwait<NL>(); }
  else vmwait<0>();
  sbar();

  for(int t=0; t<nt; ++t){
    if((t&1)==0){ COMPUTE(lA0, lB0); } else { COMPUTE(lA1, lB1); }
    if(t+1 < nt){
      sbar();
      if(t+2 < nt){
        int k0 = (t+2)*BK;
        if((t&1)==0){ STAGE_A(lA0, k0); STAGE_B(lB0, k0); }
        else        { STAGE_A(lA1, k0); STAGE_B(lB1, k0); }
        vmwait<NL>();
      } else {
        vmwait<0>();
      }
      sbar();
    }
  }

  if(EPI==0 || EPI==3 || EPI==6){
#pragma unroll
    for(int i=0;i<FM;++i){
#pragma unroll
      for(int r=0;r<4;++r){
        int m = m0 + wr*PWM + i*16 + l4*4 + r;
        if(m>=M) continue;
#pragma unroll
        for(int j=0;j<FN;++j){
          int n = n0 + wc*PWN + j*16 + l15;
          if(n>=N) continue;
          float v = acc[i][j][r];
          if(bias) v += bias[n];
          if(EPI==3) v = 0.5f*v*(1.f+erff(v*0.70710678118f));
          if(EPI==6){
            int bq = z>>3, hh = z&7;
            ((ushort_t*)Cv)[((long)(bq*196+m))*384 + hh*48 + n] = f2b(v);
          } else {
            ((ushort_t*)Cv)[(long)z*sC + (long)m*ldc + n] = f2b(v);
          }
        }
      }
    }
  } else {
    constexpr int STLD = BN+4;
    constexpr int STGR = (BM*STLD*4 <= SMEMB) ? BM :
                         ((BM/2*STLD*4 <= SMEMB) ? BM/2 : BM/4);
    constexpr int NPASS = BM/STGR;
    float* st = (float*)smem;
    __syncthreads();
    for(int p=0; p<NPASS; ++p){
      if(p) __syncthreads();
#pragma unroll
      for(int i=0;i<FM;++i){
        int rbase = wr*PWM + i*16 + l4*4 - p*STGR;
#pragma unroll
        for(int r=0;r<4;++r){
          int lr = rbase + r;
          if(lr < 0 || lr >= STGR) continue;
#pragma unroll
          for(int j=0;j<FN;++j)
            st[lr*STLD + wc*PWN + j*16 + l15] = acc[i][j][r];
        }
      }
      __syncthreads();
      const int total = STGR*BN/4;
      for(int c=tid; c<total; c+=NT){
        int row = c/(BN/4), colc = c - row*(BN/4);
        int gm = m0 + p*STGR + row;
        if(gm >= M) continue;
        int nb = n0 + colc*4;
        if(nb >= N) continue;
        f32x4 v = *(f32x4*)&st[row*STLD + colc*4];
        float* cp = (float*)Cv + (long)gm*ldc + nb;
        f32x4 bs = bias ? *(const f32x4*)(bias+nb) : f32x4{0,0,0,0};
        if(EPI==1){
          const f32x4 ax = *(const f32x4*)(aux + (long)(gm%196)*ldc + nb);
          *(f32x4*)cp = v + bs + ax;
        } else if(EPI==2){
          const f32x4 ax = *(const f32x4*)(aux + nb);
          f32x4 h = *(f32x4*)cp;
          h += ax*(v + bs);
          *(f32x4*)cp = h;
        } else {
          *(f32x4*)cp = v + bs;
        }
      }
    }
  }
}

// ---------------- qk_logits: per (b,h), S = q @ k^T -> attn[bh][196][224] ----------------
__global__ __launch_bounds__(256) void qk_logits(
  const ushort_t* __restrict__ qkvb, ushort_t* __restrict__ attn)
{
  __shared__ __align__(16) ushort_t Q[196*64];
  __shared__ __align__(16) ushort_t Kl[196*64];
  int bh = blockIdx.x; int b = bh>>3, h = bh&7;
  int tid = threadIdx.x, lane = tid&63, w = tid>>6;
  int l15 = lane&15, l4 = lane>>4;
  const ushort_t* qs = qkvb + (long)(b*196)*1152 + h*48;
  const ushort_t* ks = qs + 384;
  for(int idx=tid; idx<196*8; idx+=256){
    int row = idx>>3, c = idx&7;
    int sw = (c*16) ^ ((row&7)<<4);
    short8 t0, t1;
    if(c<6){
      t0 = *(const short8*)(qs + (long)row*1152 + c*8);
      t1 = *(const short8*)(ks + (long)row*1152 + c*8);
    } else {
      t0 = short8{0,0,0,0,0,0,0,0}; t1 = t0;
    }
    *(short8*)((char*)Q  + row*128 + sw) = t0;
    *(short8*)((char*)Kl + row*128 + sw) = t1;
  }
  __syncthreads();
  ushort_t* Srow = attn + (long)bh*196*224;
  for(int t2=w; t2<169; t2+=4){
    int mt = t2/13, nt = t2-mt*13;
    int arow = mt*16+l15; if(arow>195) arow=195;
    int brow = nt*16+l15; if(brow>195) brow=195;
    f32x4 acc = {0.f,0.f,0.f,0.f};
#pragma unroll
    for(int ks2=0;ks2<2;++ks2){
      short8 a  = *(const short8*)((char*)Q  + arow*128 + ((ks2*64 + l4*16) ^ ((arow&7)<<4)));
      short8 bf = *(const short8*)((char*)Kl + brow*128 + ((ks2*64 + l4*16) ^ ((brow&7)<<4)));
      acc = __builtin_amdgcn_mfma_f32_16x16x32_bf16(a, bf, acc, 0,0,0);
    }
#pragma unroll
    for(int r=0;r<4;++r){
      int m = mt*16 + l4*4 + r, n = nt*16 + l15;
      if(m<196 && n<196) Srow[(long)m*224 + n] = f2b(acc[r]);
    }
  }
}

// ---------------- LayerNorm: one wave per row, 4 rows/block ----------------
__global__ __launch_bounds__(256) void ln_kernel(
  const float* __restrict__ X, ushort_t* __restrict__ Y,
  const float* __restrict__ g, const float* __restrict__ b, int rows)
{
  int r = blockIdx.x*4 + (threadIdx.x>>6);
  if(r>=rows) return;
  int t = threadIdx.x & 63;
  const float* xr = X + (long)r*384;
  ushort_t* yr = Y + (long)r*384;
  f32x4  v0 = *(const f32x4*)(xr + t*4);
  float2 v1 = *(const float2*)(xr + 256 + t*2);
  float s = v0[0]+v0[1]+v0[2]+v0[3]+v1.x+v1.y;
  s = wred_sum(s);
  float mean = s*(1.f/384.f);
  float d0=v0[0]-mean, d1=v0[1]-mean, d2=v0[2]-mean, d3=v0[3]-mean,
        d4=v1.x-mean, d5=v1.y-mean;
  float ss = d0*d0+d1*d1+d2*d2+d3*d3+d4*d4+d5*d5;
  ss = wred_sum(ss);
  float rstd = rsqrtf(ss*(1.f/384.f)+EPS_);
  f32x4  g0 = *(const f32x4*)(g + t*4);
  float2 g1 = *(const float2*)(g + 256 + t*2);
  f32x4  b0 = *(const f32x4*)(b + t*4);
  float2 b1 = *(const float2*)(b + 256 + t*2);
  us4 o0;
  o0[0]=f2b(d0*rstd*g0[0]+b0[0]); o0[1]=f2b(d1*rstd*g0[1]+b0[1]);
  o0[2]=f2b(d2*rstd*g0[2]+b0[2]); o0[3]=f2b(d3*rstd*g0[3]+b0[3]);
  *(us4*)(yr + t*4) = o0;
  unsigned int ot = (unsigned int)f2b(d4*rstd*g1.x+b1.x) |
                    ((unsigned int)f2b(d5*rstd*g1.y+b1.y)<<16);
  *(unsigned int*)(yr + 256 + t*2) = ot;
}

// ---------------- talking-heads mix + softmax + mix, in place ----------------
__global__ __launch_bounds__(256) void th_softmax(
  ushort_t* attn,
  const float* __restrict__ plw, const float* __restrict__ plb,
  const float* __restrict__ pww, const float* __restrict__ pwb)
{
  __shared__ float swl[64], sww[64], sbl[8], sbw[8];
  int t = threadIdx.x;
  if(t<64){ swl[t]=plw[t]; sww[t]=pww[t]; }
  if(t<8){ sbl[t]=plb[t]; sbw[t]=pwb[t]; }
  __syncthreads();
  int wid = t>>6, lane = t&63;
  int rid = blockIdx.x*4 + wid;
  int b = rid/196, n = rid - b*196;
  long rbase = ((long)(b*8)*196 + n)*224;
  int col0 = lane*4;
  bool inrow = col0 < 224;
  bool act = col0 < 196;
  float L[8][4];
#pragma unroll
  for(int h=0;h<8;++h){
    us4 v = inrow ? *(const us4*)(attn + rbase + (long)h*43904 + col0) : us4{0,0,0,0};
#pragma unroll
    for(int c=0;c<4;++c) L[h][c] = b2f(v[c]);
  }
  float P[8][4];
#pragma unroll
  for(int g=0; g<8; ++g){
    float mv[4];
#pragma unroll
    for(int c=0;c<4;++c){
      float v = sbl[g];
#pragma unroll
      for(int h=0;h<8;++h) v += L[h][c]*swl[g*8+h];
      mv[c] = act ? v : -3.0e38f;
    }
    float mx = fmaxf(fmaxf(mv[0],mv[1]),fmaxf(mv[2],mv[3]));
    mx = wred_max(mx);
    float sum = 0.f;
#pragma unroll
    for(int c=0;c<4;++c){
      float e = act ? exp2f((mv[c]-mx)*LOG2E_) : 0.f;
      P[g][c] = e; sum += e;
    }
    sum = wred_sum(sum);
    float rinv = 1.f/sum;
#pragma unroll
    for(int c=0;c<4;++c) P[g][c] *= rinv;
  }
#pragma unroll
  for(int g2=0; g2<8; ++g2){
    us4 st;
#pragma unroll
    for(int c=0;c<4;++c){
      float v = sbw[g2];
#pragma unroll
      for(int g=0; g<8; ++g) v += P[g][c]*sww[g2*8+g];
      st[c] = f2b(v);
    }
    if(act) *(us4*)(attn + ((long)(b*8+g2)*196 + n)*224 + col0) = st;
  }
}

// ---------------- V transpose: qkvb v-cols -> vT[bh][48][224] ----------------
__global__ __launch_bounds__(256) void v_transpose(
  const ushort_t* __restrict__ qkvb, ushort_t* __restrict__ vT)
{
  int bh = blockIdx.x; int b = bh>>3, h = bh&7;
  int p0 = blockIdx.y*98;
  __shared__ ushort_t tile[98*49];
  int t = threadIdx.x;
  const ushort_t* src = qkvb + (long)(b*196+p0)*1152 + 768 + h*48;
  for(int idx=t; idx<98*48; idx+=256){
    int p = idx/48, d = idx - p*48;
    tile[p*49+d] = src[(long)p*1152 + d];
  }
  __syncthreads();
  ushort_t* dst = vT + ((long)bh*48)*224 + p0;
  for(int idx=t; idx<48*98; idx+=256){
    int d = idx/98, p = idx - d*98;
    dst[(long)d*224 + p] = tile[p*49+d];
  }
}

// ---------------- class-attention (1 query token), kv packed [12608][768] ----------------
__global__ __launch_bounds__(256) void ca_attn_kernel(
  const ushort_t* __restrict__ q, const ushort_t* __restrict__ kv,
  ushort_t* __restrict__ o)
{
  int bh = blockIdx.x; int b = bh>>3, h = bh&7;
  int t = threadIdx.x;
  __shared__ float qs[48], p[197], sm[4];
  if(t<48) qs[t] = b2f(q[(long)b*384 + h*48 + t]) * 0.14433756729740643f;
  __syncthreads();
  float logit = -3.0e38f;
  if(t<197){
    const ushort_t* kr = kv + ((long)(b*197+t))*768 + h*48;
    float s=0.f;
#pragma unroll
    for(int d=0;d<48;++d) s += qs[d]*b2f(kr[d]);
    logit = s;
  }
  float mx = bred256_max(logit, sm);
  float e = (t<197)? expf(logit-mx):0.f;
  float ssum = bred256_sum(e, sm);
  if(t<197) p[t] = e/ssum;
  __syncthreads();
  if(t<48){
    const ushort_t* vr = kv + (long)b*197*768 + 384 + h*48 + t;
    float s=0.f;
    for(int m=0;m<197;++m) s += p[m]*b2f(vr[(long)m*768]);
    o[(long)b*384 + h*48 + t] = f2b(s);
  }
}

// ---------------- small elementwise kernels ----------------
__global__ void patch_extract(const float* __restrict__ x, ushort_t* __restrict__ xp){
  long i = (long)blockIdx.x*256 + threadIdx.x;
  if(i >= (long)12544*768) return;
  int kk = (int)(i % 768); long row = i/768;
  int b = (int)(row/196), pidx = (int)(row%196);
  int gy = pidx/14, gx = pidx%14;
  int ch = kk/256, r = kk%256, py = r/16, px = r%16;
  xp[i] = f2b(x[((long)(b*3+ch)*224 + gy*16+py)*224 + gx*16+px]);
}
__global__ void build_u(const float* __restrict__ h, float* __restrict__ u){
  long i = (long)blockIdx.x*256 + threadIdx.x;
  if(i >= (long)12544*384) return;
  int c = (int)(i % 384); long rp = i/384;
  int b = (int)(rp/196), p = (int)(rp%196);
  u[((long)b*197 + 1 + p)*384 + c] = h[i];
}
__global__ void set_row0(float* __restrict__ u, const float* __restrict__ cls){
  int i = blockIdx.x*256 + threadIdx.x;
  if(i >= 64*384) return;
  int b = i/384, c = i%384;
  u[(long)b*197*384 + c] = cls[i];
}
__global__ void init_cls(float* __restrict__ cls, const float* __restrict__ tok){
  int i = blockIdx.x*256 + threadIdx.x;
  if(i >= 64*384) return;
  cls[i] = tok[i%384];
}
__global__ void conv_bf(const float* __restrict__ s, ushort_t* __restrict__ d, int n){
  int i = (blockIdx.x*256 + threadIdx.x)*4;
  if(i+3 < n){
    float4 v = *(const float4*)(s+i);
    d[i]=f2b(v.x); d[i+1]=f2b(v.y); d[i+2]=f2b(v.z); d[i+3]=f2b(v.w);
  } else {
    for(int j=i;j<n;++j) d[j]=f2b(s[j]);
  }
}
__global__ void conv_qkv(const float* __restrict__ w, ushort_t* __restrict__ out, float scl){
  long i = (long)blockIdx.x*256 + threadIdx.x;
  if(i >= 5308416L) return;
  long r = i / 384;
  int n = (int)(r % 1152);
  float v = w[i];
  if(n < 384) v *= scl;
  out[i] = f2b(v);
}

// ---------------- host orchestration ----------------
extern "C" void kernel_launch(void* const* d_in, const int* in_sizes, int n_in,
                              void* d_out, int out_size, void* d_ws, size_t ws_size,
                              hipStream_t stream)
{
  const float* in_x     = (const float*)d_in[0];
  const float* patch_w  = (const float*)d_in[1];
  const float* patch_b  = (const float*)d_in[2];
  const float* cls_tok  = (const float*)d_in[3];
  const float* pos_emb  = (const float*)d_in[4];
  const float* ln1_g = (const float*)d_in[5];
  const float* ln1_b = (const float*)d_in[6];
  const float* qkv_w = (const float*)d_in[7];
  const float* proj_w = (const float*)d_in[8];
  const float* proj_b = (const float*)d_in[9];
  const float* pl_w = (const float*)d_in[10];
  const float* pl_b = (const float*)d_in[11];
  const float* pw_w = (const float*)d_in[12];
  const float* pw_b = (const float*)d_in[13];
  const float* ln2_g = (const float*)d_in[14];
  const float* ln2_b = (const float*)d_in[15];
  const float* fc1_w = (const float*)d_in[16];
  const float* fc1_b = (const float*)d_in[17];
  const float* fc2_w = (const float*)d_in[18];
  const float* fc2_b = (const float*)d_in[19];
  const float* g1 = (const float*)d_in[20];
  const float* g2 = (const float*)d_in[21];
  const float* ca_ln1_g = (const float*)d_in[22];
  const float* ca_ln1_b = (const float*)d_in[23];
  const float* ca_q_w = (const float*)d_in[24];
  const float* ca_k_w = (const float*)d_in[25];
  const float* ca_v_w = (const float*)d_in[26];
  const float* ca_proj_w = (const float*)d_in[27];
  const float* ca_proj_b = (const float*)d_in[28];
  const float* ca_ln2_g = (const float*)d_in[29];
  const float* ca_ln2_b = (const float*)d_in[30];
  const float* ca_fc1_w = (const float*)d_in[31];
  const float* ca_fc1_b = (const float*)d_in[32];
  const float* ca_fc2_w = (const float*)d_in[33];
  const float* ca_fc2_b = (const float*)d_in[34];
  const float* ca_g1 = (const float*)d_in[35];
  const float* ca_g2 = (const float*)d_in[36];
  const float* norm_g = (const float*)d_in[37];
  const float* norm_b = (const float*)d_in[38];
  const float* head_w = (const float*)d_in[39];
  const float* head_b = (const float*)d_in[40];
  float* out = (float*)d_out;

  // ---- workspace layout (bytes) ----
  char* W0 = (char*)d_ws;
  float*    h_buf  = (float*)   (W0 + 0);          // 12544*384 f32
  ushort_t* attn   = (ushort_t*)(W0 + 19267584);   // [512][196][224] bf16 (aliases u/xp)
  float*    u_buf  = (float*)attn;
  ushort_t* xp_bf  = (ushort_t*)attn;
  float*    cls    = (float*)   (W0 + 64225280);
  ushort_t* ln_bf  = (ushort_t*)(W0 + 64323584);   // 12608*384 bf16
  ushort_t* qkvb   = (ushort_t*)(W0 + 74006528);   // [12544][1152] bf16
  ushort_t* vT     = (ushort_t*)(W0 + 102907904);  // [512][48][224] bf16
  ushort_t* wb     = (ushort_t*)(W0 + 113917952);  // weights
  ushort_t* cq_bf  = (ushort_t*)(W0 + 164820992);
  ushort_t* oca_bf = (ushort_t*)(W0 + 164870144);
  ushort_t* clsln  = (ushort_t*)(W0 + 164919296);
  ushort_t* mlpca  = (ushort_t*)(W0 + 164968448);
  ushort_t* mlp_bf = (ushort_t*)(W0 + 165165056);  // [12544][1536] bf16
  ushort_t* o_bf   = qkvb;                         // o [12544][384]
  ushort_t* kv_bf  = qkvb;                         // CA kv [12608][768]

  const long WP=0, WQKV=294912, WPROJ=5603328, WFC1=7372800, WFC2=14450688,
             WCAQ=21528576, WCAK=21823488, WCAP=22413312,
             WCAF1=22708224, WCAF2=23887872, WHEAD=25067520;

  const float scl = 0.14433756729740643f;  // 48^-0.5
  dim3 blk(256);

  // zero vT once (cols >=196 must stay 0)
  hipMemsetAsync(vT, 0, 11010048, stream);

  // weights -> bf16 (qkv natural layout, q rows prescaled)
  conv_qkv<<<dim3(20736),blk,0,stream>>>(qkv_w, wb+WQKV, scl);
  {
    const float* src[11] = {patch_w,proj_w,fc1_w,fc2_w,ca_q_w,ca_k_w,ca_v_w,
                            ca_proj_w,ca_fc1_w,ca_fc2_w,head_w};
    const long  off[11] = {WP,WPROJ,WFC1,WFC2,WCAQ,WCAK,WCAK+294912,WCAP,WCAF1,WCAF2,WHEAD};
    const long  cnt[11] = {294912,1769472,7077888,7077888,294912,294912,294912,
                           294912,1179648,1179648,384000};
    for(int i=0;i<11;++i)
      conv_bf<<<dim3((unsigned)((cnt[i]/4+255)/256)),blk,0,stream>>>(src[i], wb+off[i], (int)cnt[i]);
  }

  // 1. patch embed (xp aliases attn; runs before attn memset)
  {
    long n = (long)12544*768;
    patch_extract<<<dim3((unsigned)((n+255)/256)), blk, 0, stream>>>(in_x, xp_bf);
  }
  gemm_bf<128,128,64,512,4,2,1><<<dim3(3,98,1),dim3(512),0,stream>>>(xp_bf,768,0,0, wb+WP,768,0,0, patch_b,
      h_buf,384,0, 12544,384,768,1, pos_emb);

  // zero attn once: pads (col>=196) stay zero across all layers
  hipMemsetAsync(attn, 0, 44957696, stream);

  // 2. twelve talking-heads SA blocks
  for(int d=0; d<12; ++d){
    ln_kernel<<<3136,blk,0,stream>>>(h_buf, ln_bf, ln1_g+d*384, ln1_b+d*384, 12544);
    gemm_bf<128,128,64,512,4,2,0><<<dim3(9,98,1),dim3(512),0,stream>>>(ln_bf,384,0,0,
        wb+WQKV+(long)d*442368,384,0,0, nullptr,
        qkvb,1152,0, 12544,1152,384,1, nullptr);
    v_transpose<<<dim3(512,2,1),blk,0,stream>>>(qkvb, vT);
    qk_logits<<<dim3(512),blk,0,stream>>>(qkvb, attn);
    th_softmax<<<3136,blk,0,stream>>>(attn, pl_w+d*64, pl_b+d*8, pw_w+d*64, pw_b+d*8);
    gemm_bf<64,64,32,256,2,2,6><<<dim3(1,4,512),blk,0,stream>>>(attn,224,43904L,0L,
        vT,224,10752L,0L, nullptr,
        o_bf,0,0, 196,48,224,1, nullptr);
    gemm_bf<128,128,64,512,4,2,2><<<dim3(3,98,1),dim3(512),0,stream>>>(o_bf,384,0,0,
        wb+WPROJ+(long)d*147456,384,0,0, proj_b+d*384,
        h_buf,384,0, 12544,384,384,1, g1+d*384);
    ln_kernel<<<3136,blk,0,stream>>>(h_buf, ln_bf, ln2_g+d*384, ln2_b+d*384, 12544);
    gemm_bf<128,128,64,512,4,2,3><<<dim3(12,98,1),dim3(512),0,stream>>>(ln_bf,384,0,0,
        wb+WFC1+(long)d*589824,384,0,0, fc1_b+d*1536,
        mlp_bf,1536,0, 12544,1536,384,1, nullptr);
    gemm_bf<128,128,64,512,4,2,2><<<dim3(3,98,1),dim3(512),0,stream>>>(mlp_bf,1536,0,0,
        wb+WFC2+(long)d*589824,1536,0,0, fc2_b+d*384,
        h_buf,384,0, 12544,384,1536,1, g2+d*384);
  }

  // 3. two class-attention blocks
  init_cls<<<96,blk,0,stream>>>(cls, cls_tok);
  build_u<<<dim3((unsigned)(((long)12544*384+255)/256)),blk,0,stream>>>(h_buf, u_buf);
  for(int d=0; d<2; ++d){
    set_row0<<<96,blk,0,stream>>>(u_buf, cls);
    ln_kernel<<<3152,blk,0,stream>>>(u_buf, ln_bf, ca_ln1_g+d*384, ca_ln1_b+d*384, 12608);
    gemm_bf<64,64,64,256,2,2,0><<<dim3(6,1,1),blk,0,stream>>>(ln_bf,75648,0,0,
        wb+WCAQ+(long)d*147456,384,0,0, nullptr,
        cq_bf,384,0, 64,384,384,1, nullptr);
    gemm_bf<128,128,64,512,4,2,0><<<dim3(6,99,1),dim3(512),0,stream>>>(ln_bf,384,0,0,
        wb+WCAK+(long)d*147456,384,0,0, nullptr,
        kv_bf,768,0, 12608,768,384,1, nullptr);
    ca_attn_kernel<<<512,blk,0,stream>>>(cq_bf, kv_bf, oca_bf);
    gemm_bf<64,64,64,256,2,2,2><<<dim3(6,1,1),blk,0,stream>>>(oca_bf,384,0,0,
        wb+WCAP+(long)d*147456,384,0,0, ca_proj_b+d*384,
        cls,384,0, 64,384,384,1, ca_g1+d*384);
    ln_kernel<<<16,blk,0,stream>>>(cls, clsln, ca_ln2_g+d*384, ca_ln2_b+d*384, 64);
    gemm_bf<64,64,64,256,2,2,3><<<dim3(24,1,1),blk,0,stream>>>(clsln,384,0,0,
        wb+WCAF1+(long)d*589824,384,0,0, ca_fc1_b+d*1536,
        mlpca,1536,0, 64,1536,384,1, nullptr);
    gemm_bf<64,64,64,256,2,2,2><<<dim3(6,1,1),blk,0,stream>>>(mlpca,1536,0,0,
        wb+WCAF2+(long)d*589824,1536,0,0, ca_fc2_b+d*384,
        cls,384,0, 64,384,1536,1, ca_g2+d*384);
  }

  // 4. final LN (cls rows) + head
  ln_kernel<<<16,blk,0,stream>>>(cls, clsln, norm_g, norm_b, 64);
  gemm_bf<64,64,64,256,2,2,7><<<dim3(16,1,1),blk,0,stream>>>(clsln,384,0,0, wb+WHEAD,384,0,0, head_b,
      out,1000,0, 64,1000,384,1, nullptr);
}